// Round 10
// baseline (57.240 us; speedup 1.0000x reference)
//
#include <hip/hip_runtime.h>
#include <hip/hip_bf16.h>

#define BB 2
#define TT 1024
#define DD 512
#define HH 8
#define FF 16
#define HDIM 64
#define BT (BB*TT)   // 2048

typedef short bf16x8 __attribute__((ext_vector_type(8)));
typedef float f32x4  __attribute__((ext_vector_type(4)));
#define MFMA_BF16 __builtin_amdgcn_mfma_f32_16x16x32_bf16

// float -> bf16 round-to-nearest-even (scalar)
__device__ __forceinline__ ushort f2b(float f) {
    uint u = __float_as_uint(f);
    uint r = (u + 0x7fffu + ((u >> 16) & 1u)) >> 16;
    return (ushort)r;
}

// pack two floats -> one dword of 2 bf16 (v_cvt_pk_bf16_f32)
__device__ __forceinline__ uint pkbf2(float a, float b) {
    __hip_bfloat162 h = __float22bfloat162_rn(make_float2(a, b));
    union { __hip_bfloat162 h2; uint u; } c; c.h2 = h;
    return c.u;
}

// raw 8-float register block (prefetchable) + conversion to MFMA fragment
struct fr8 { float4 a, b; };
__device__ __forceinline__ fr8 ld8(const float* p) {
    fr8 r; r.a = *(const float4*)p; r.b = *(const float4*)(p + 4); return r;
}
__device__ __forceinline__ bf16x8 c8(const fr8& x) {
    union { bf16x8 v; uint u[4]; } r;
    r.u[0] = pkbf2(x.a.x, x.a.y);
    r.u[1] = pkbf2(x.a.z, x.a.w);
    r.u[2] = pkbf2(x.b.x, x.b.y);
    r.u[3] = pkbf2(x.b.z, x.b.w);
    return r.v;
}

// ---------------------------------------------------------------------------
// Kernel 1: QKV projection, bf16 MFMA, f32 inputs converted inline (no cast
// dispatch).  C[2048 x 768] = X @ [Wq;Wk;Wv]^T, K=512.  Grid (32,13), 512
// threads: by 0..11 = 64x64 GEMM tiles, 8 waves = (2m x 2n) x 2k, wave 32x32
// over K=256, raw-f32 prefetch-1 (loads fly under cvt+MFMA of current iter).
// by==12 casts Wo -> Wob (consumed 2 dispatches later).
// f32 LDS combine, route: Q,K -> (bh,t,16) bf16; V -> Vt[bh][64][1024].
// ---------------------------------------------------------------------------
__global__ __launch_bounds__(512) void qkv_mfma(
    const float* __restrict__ X,  const float* __restrict__ Wq,
    const float* __restrict__ Wk, const float* __restrict__ Wv,
    const float* __restrict__ Wo,
    ushort* __restrict__ Qb, ushort* __restrict__ Kb,
    ushort* __restrict__ Vtg, ushort* __restrict__ Wob)
{
    if (blockIdx.y == 12) {   // Wo cast tail: 32 blocks x 512 thr x 4 float4
        const int idx = blockIdx.x * 512 + threadIdx.x;   // 0..16383
        #pragma unroll
        for (int j = 0; j < 4; ++j) {
            const int u = j * 16384 + idx;                // 0..65535 float4s
            float4 v = *(const float4*)(Wo + (size_t)u * 4);
            ushort4 o = { f2b(v.x), f2b(v.y), f2b(v.z), f2b(v.w) };
            *(ushort4*)(Wob + (size_t)u * 4) = o;
        }
        return;
    }

    __shared__ float sc[2][64][66];
    const int m0 = blockIdx.x * 64, n0 = blockIdx.y * 64;
    const int tid = threadIdx.x, w = tid >> 6, l = tid & 63;
    const int kw = w >> 2, mw = w & 1, nw = (w >> 1) & 1;
    const int lr = l & 15, g = l >> 4;

    const float* Wsrc; int nb0;
    if (n0 < 128)      { Wsrc = Wq; nb0 = n0; }
    else if (n0 < 256) { Wsrc = Wk; nb0 = n0 - 128; }
    else               { Wsrc = Wv; nb0 = n0 - 256; }

    f32x4 acc[2][2] = {};
    const float* Ar = X    + (size_t)(m0 + mw*32 + lr) * 512 + kw*256 + g*8;
    const float* Br = Wsrc + (size_t)(nb0 + nw*32 + lr) * 512 + kw*256 + g*8;

    fr8 A0 = ld8(Ar);
    fr8 A1 = ld8(Ar + (size_t)16*512);
    fr8 B0 = ld8(Br);
    fr8 B1 = ld8(Br + (size_t)16*512);
    #pragma unroll
    for (int ks = 0; ks < 8; ++ks) {
        fr8 A0n, A1n, B0n, B1n;
        if (ks < 7) {
            A0n = ld8(Ar + (ks+1)*32);
            A1n = ld8(Ar + (size_t)16*512 + (ks+1)*32);
            B0n = ld8(Br + (ks+1)*32);
            B1n = ld8(Br + (size_t)16*512 + (ks+1)*32);
        }
        bf16x8 a0 = c8(A0), a1 = c8(A1), b0 = c8(B0), b1 = c8(B1);
        acc[0][0] = MFMA_BF16(a0, b0, acc[0][0], 0, 0, 0);
        acc[0][1] = MFMA_BF16(a0, b1, acc[0][1], 0, 0, 0);
        acc[1][0] = MFMA_BF16(a1, b0, acc[1][0], 0, 0, 0);
        acc[1][1] = MFMA_BF16(a1, b1, acc[1][1], 0, 0, 0);
        if (ks < 7) { A0 = A0n; A1 = A1n; B0 = B0n; B1 = B1n; }
    }

    #pragma unroll
    for (int mb = 0; mb < 2; ++mb)
        #pragma unroll
        for (int nb = 0; nb < 2; ++nb)
            #pragma unroll
            for (int r = 0; r < 4; ++r)
                sc[kw][mw*32 + mb*16 + g*4 + r][nw*32 + nb*16 + lr] = acc[mb][nb][r];
    __syncthreads();

    // combine K-halves + route.  thread: col vl, rows rg*8..rg*8+7
    const int vl = tid & 63, rg = tid >> 6;
    const int cg = n0 + vl;
    float v8[8];
    #pragma unroll
    for (int j = 0; j < 8; ++j) v8[j] = sc[0][rg*8 + j][vl] + sc[1][rg*8 + j][vl];
    const int tok0 = m0 + rg*8;
    const int b = tok0 >> 10, tt0 = tok0 & 1023;
    if (cg < 256) {
        const bool isQ = cg < 128;
        const int c = isQ ? cg : cg - 128;
        const int h = c >> 4, f = c & 15;
        ushort* Dst = isQ ? Qb : Kb;
        #pragma unroll
        for (int j = 0; j < 8; ++j)
            Dst[((size_t)(b*HH + h)*TT + tt0 + j)*FF + f] = f2b(v8[j]);
    } else {
        const int c = cg - 256;
        const int h = c >> 6, v = c & 63;
        uint2 p0 = { pkbf2(v8[0], v8[1]), pkbf2(v8[2], v8[3]) };
        uint2 p1 = { pkbf2(v8[4], v8[5]), pkbf2(v8[6], v8[7]) };
        ushort* base = Vtg + ((size_t)(b*HH + h)*64 + v)*TT + tt0;
        *(uint2*)base       = p0;
        *(uint2*)(base + 4) = p1;
    }
}

// ---------------------------------------------------------------------------
// Kernel 2: causal Taylor attention, bf16 MFMA, 8-wave split-K.
// (byte-identical to round 9)
// ---------------------------------------------------------------------------
__global__ __launch_bounds__(512) void attn_mfma(
    const ushort* __restrict__ Qb, const ushort* __restrict__ Kb,
    const ushort* __restrict__ Vtg, ushort* __restrict__ Yb)
{
    __shared__ float smem[8*32*68 + 8*32];           // 70656 B
    short (*Pl)[32][72] = (short(*)[32][72])smem;    // [wave][q32][k64+8]
    float* scf = smem;                               // epi: [8][32][68]
    float* scd = smem + 8*32*68;                     // epi: [8][32]

    const int bid = blockIdx.x;
    const int qt = 31 - (bid >> 4);       // heavy q-tiles dispatch first (LPT)
    const int bh = bid & 15;
    const int b = bh >> 3, h = bh & 7;
    const int tid = threadIdx.x, w = tid >> 6, l = tid & 63;
    const int lr = l & 15, g = l >> 4;
    const int nkc = (qt + 2) >> 1;        // ceil((qt+1)*32/64)
    const bf16x8 zf = {0,0,0,0,0,0,0,0};

    bf16x8 qf[2];
    #pragma unroll
    for (int nb = 0; nb < 2; ++nb)
        qf[nb] = (l < 32)
            ? *(const bf16x8*)(Qb + ((size_t)bh*TT + qt*32 + nb*16 + lr)*FF + g*8)
            : zf;

    f32x4 o[4][2] = {};       // o[mv][nb]: O^T partial over this wave's kc set
    float den[2] = {0.f, 0.f};

    for (int kc = w; kc < nkc; kc += 8) {
        #pragma unroll
        for (int mb = 0; mb < 4; ++mb) {
            bf16x8 kf = (l < 32)
                ? *(const bf16x8*)(Kb + ((size_t)bh*TT + kc*64 + mb*16 + lr)*FF + g*8)
                : zf;
            #pragma unroll
            for (int nb = 0; nb < 2; ++nb) {
                f32x4 z4 = {};
                f32x4 s = MFMA_BF16(kf, qf[nb], z4, 0, 0, 0);
                const int qg = qt*32 + nb*16 + lr;
                const int kg0 = kc*64 + mb*16 + g*4;
                float pv[4];
                #pragma unroll
                for (int r = 0; r < 4; ++r) {
                    float ss = s[r] * 0.25f;
                    float pp = fmaf(ss, fmaf(ss, 0.5f, 1.0f), 1.0f);
                    if (kg0 + r > qg) pp = 0.f;
                    den[nb] += pp;
                    pv[r] = pp;
                }
                uint2 pk = { pkbf2(pv[0], pv[1]), pkbf2(pv[2], pv[3]) };
                *(uint2*)&Pl[w][nb*16 + lr][mb*16 + g*4] = pk;
            }
        }

        #pragma unroll
        for (int kb = 0; kb < 2; ++kb)
            #pragma unroll
            for (int mv = 0; mv < 4; ++mv) {
                bf16x8 vf = *(const bf16x8*)(Vtg +
                    ((size_t)bh*64 + mv*16 + lr)*TT + kc*64 + kb*32 + g*8);
                #pragma unroll
                for (int nb = 0; nb < 2; ++nb) {
                    bf16x8 pf = *(const bf16x8*)&Pl[w][nb*16 + lr][kb*32 + g*8];
                    o[mv][nb] = MFMA_BF16(vf, pf, o[mv][nb], 0, 0, 0);
                }
            }
    }

    float dred[2];
    #pragma unroll
    for (int nb = 0; nb < 2; ++nb) {
        float d = den[nb];
        d += __shfl_xor(d, 16);
        d += __shfl_xor(d, 32);
        dred[nb] = d;
    }

    __syncthreads();   // all waves done with Pl (scratch overlays it)

    #pragma unroll
    for (int mv = 0; mv < 4; ++mv)
        #pragma unroll
        for (int nb = 0; nb < 2; ++nb)
            *(f32x4*)&scf[(size_t)(w*32 + nb*16 + lr)*68 + mv*16 + g*4] = o[mv][nb];
    if (g == 0) {
        scd[w*32 + lr]      = dred[0];
        scd[w*32 + 16 + lr] = dred[1];
    }

    __syncthreads();

    // combine 8 wave-partials, normalize, store bf16 Y (8B/thread coalesced)
    {
        const int q  = tid >> 4;           // 0..31
        const int v0 = (tid & 15) * 4;     // 0..60
        float dtot = 0.f;
        #pragma unroll
        for (int ww = 0; ww < 8; ++ww) dtot += scd[ww*32 + q];
        const float inv = 1.0f / (dtot + 1e-12f);
        float o0 = 0.f, o1 = 0.f, o2 = 0.f, o3 = 0.f;
        #pragma unroll
        for (int ww = 0; ww < 8; ++ww) {
            const float* p = &scf[(size_t)(ww*32 + q)*68 + v0];
            o0 += p[0]; o1 += p[1]; o2 += p[2]; o3 += p[3];
        }
        uint2 pk = { pkbf2(o0*inv, o1*inv), pkbf2(o2*inv, o3*inv) };
        *(uint2*)(Yb + ((size_t)(b*TT + qt*32 + q))*DD + h*HDIM + v0) = pk;
    }
}

// ---------------------------------------------------------------------------
// Kernel 3: output projection, bf16 MFMA, K-split 8-wave latency structure.
// (byte-identical to round 9)
// ---------------------------------------------------------------------------
__global__ __launch_bounds__(512) void out_mfma(
    const ushort* __restrict__ Yb, const ushort* __restrict__ Wob,
    float* __restrict__ Out)
{
    __shared__ float sc[2][64][66];
    const int m0 = blockIdx.x * 64, n0 = blockIdx.y * 64;
    const int tid = threadIdx.x, w = tid >> 6, l = tid & 63;
    const int kw = w >> 2, mw = w & 1, nw = (w >> 1) & 1;
    const int lr = l & 15, g = l >> 4;

    f32x4 acc[2][2] = {};
    const ushort* Ar = Yb  + (size_t)(m0 + mw*32 + lr) * 512 + kw*256 + g*8;
    const ushort* Br = Wob + (size_t)(n0 + nw*32 + lr) * 512 + kw*256 + g*8;

    bf16x8 a0c = *(const bf16x8*)(Ar);
    bf16x8 a1c = *(const bf16x8*)(Ar + (size_t)16*512);
    bf16x8 b0c = *(const bf16x8*)(Br);
    bf16x8 b1c = *(const bf16x8*)(Br + (size_t)16*512);
    #pragma unroll
    for (int ks = 0; ks < 8; ++ks) {
        bf16x8 a0n = a0c, a1n = a1c, b0n = b0c, b1n = b1c;
        if (ks < 7) {
            a0n = *(const bf16x8*)(Ar + (ks+1)*32);
            a1n = *(const bf16x8*)(Ar + (size_t)16*512 + (ks+1)*32);
            b0n = *(const bf16x8*)(Br + (ks+1)*32);
            b1n = *(const bf16x8*)(Br + (size_t)16*512 + (ks+1)*32);
        }
        acc[0][0] = MFMA_BF16(a0c, b0c, acc[0][0], 0, 0, 0);
        acc[0][1] = MFMA_BF16(a0c, b1c, acc[0][1], 0, 0, 0);
        acc[1][0] = MFMA_BF16(a1c, b0c, acc[1][0], 0, 0, 0);
        acc[1][1] = MFMA_BF16(a1c, b1c, acc[1][1], 0, 0, 0);
        a0c = a0n; a1c = a1n; b0c = b0n; b1c = b1n;
    }

    #pragma unroll
    for (int mb = 0; mb < 2; ++mb)
        #pragma unroll
        for (int nb = 0; nb < 2; ++nb)
            #pragma unroll
            for (int r = 0; r < 4; ++r)
                sc[kw][mw*32 + mb*16 + g*4 + r][nw*32 + nb*16 + lr] = acc[mb][nb][r];
    __syncthreads();

    const int vl = tid & 63, rg = tid >> 6;
    #pragma unroll
    for (int j = 0; j < 8; ++j) {
        const float v = sc[0][rg*8 + j][vl] + sc[1][rg*8 + j][vl];
        Out[(size_t)(m0 + rg*8 + j)*512 + n0 + vl] = v;
    }
}

// ---------------------------------------------------------------------------
extern "C" void kernel_launch(void* const* d_in, const int* in_sizes, int n_in,
                              void* d_out, int out_size, void* d_ws, size_t ws_size,
                              hipStream_t stream) {
    const float* X  = (const float*)d_in[0];   // (2,1024,512)
    const float* Wq = (const float*)d_in[1];   // (128,512)
    const float* Wk = (const float*)d_in[2];   // (128,512)
    const float* Wv = (const float*)d_in[3];   // (512,512)
    const float* Wo = (const float*)d_in[4];   // (512,512)
    float* out = (float*)d_out;                // (2,1024,512)

    ushort* ws = (ushort*)d_ws;
    ushort* Wob = ws;                    // 512*512    = 262144
    ushort* Qb  = Wob + 262144;          // 16*1024*16 = 262144
    ushort* Kb  = Qb  + 262144;          // 262144
    ushort* Vtg = Kb  + 262144;          // 16*64*1024 = 1048576
    ushort* Yb  = Vtg + 1048576;         // 2048*512   = 1048576
    // total 2,883,584 ushorts = 5.8 MB

    dim3 g1(BT/64, 13);       // 32 x 12 GEMM + 32 x 1 Wo-cast = 416 blocks
    qkv_mfma<<<g1, 512, 0, stream>>>(X, Wq, Wk, Wv, Wo, Qb, Kb, Vtg, Wob);

    attn_mfma<<<512, 512, 0, stream>>>(Qb, Kb, Vtg, Yb);

    dim3 g3(BT/64, DD/64);    // 32 x 8 = 256 blocks, 512 thr
    out_mfma<<<g3, 512, 0, stream>>>(Yb, Wob, out);
}